// Round 3
// baseline (372.837 us; speedup 1.0000x reference)
//
#include <hip/hip_runtime.h>
#include <hip/hip_bf16.h>

typedef __attribute__((ext_vector_type(8))) short short8;
typedef __attribute__((ext_vector_type(4))) short short4v;
typedef __attribute__((ext_vector_type(4))) float f32x4;

static inline size_t ws_align(size_t x) { return (x + 511) & ~((size_t)511); }

static __device__ inline unsigned short f2bf(float f) {
    __hip_bfloat16 h = __float2bfloat16(f);
    return __builtin_bit_cast(unsigned short, h);
}

static __device__ inline float bf2f(unsigned short u) {
    unsigned int x = ((unsigned int)u) << 16;
    return __builtin_bit_cast(float, x);
}

// ---------------- dtype sniffing ----------------
// flags[0] = 1 if float inputs are fp32 (else bf16)
// flags[1] = 1 if edge_index is int64 (else int32)
__global__ void sniff_kernel(const unsigned short* __restrict__ w1,
                             const unsigned int* __restrict__ ei,
                             int* __restrict__ flags) {
    int i = threadIdx.x;  // 64 threads
    unsigned e = (w1[2 * i] >> 7) & 0xFF;
    unsigned long long m1 = __ballot(e >= 100 && e <= 130);
    unsigned long long m2 = __ballot(ei[2 * i + 1] == 0u);
    if (i == 0) {
        flags[0] = (__popcll(m1) < 48) ? 1 : 0;
        flags[1] = (__popcll(m2) >= 48) ? 1 : 0;
    }
}

// ---------------- X -> bf16 (copy if already bf16) ----------------
__global__ __launch_bounds__(256) void xconv_kernel(const void* __restrict__ Xraw,
                                                    const int* __restrict__ flags,
                                                    unsigned short* __restrict__ Xb,
                                                    long long total8) {
    long long stride = (long long)gridDim.x * 256;
    if (flags[0]) {
        const float* Xf = (const float*)Xraw;
        for (long long i = blockIdx.x * 256LL + threadIdx.x; i < total8; i += stride) {
            float4 f0 = *(const float4*)(const void*)(Xf + i * 8);
            float4 f1 = *(const float4*)(const void*)(Xf + i * 8 + 4);
            short8 r;
            r[0] = (short)f2bf(f0.x); r[1] = (short)f2bf(f0.y);
            r[2] = (short)f2bf(f0.z); r[3] = (short)f2bf(f0.w);
            r[4] = (short)f2bf(f1.x); r[5] = (short)f2bf(f1.y);
            r[6] = (short)f2bf(f1.z); r[7] = (short)f2bf(f1.w);
            *(short8*)(void*)(Xb + i * 8) = r;
        }
    } else {
        const unsigned short* Xs = (const unsigned short*)Xraw;
        for (long long i = blockIdx.x * 256LL + threadIdx.x; i < total8; i += stride) {
            *(short8*)(void*)(Xb + i * 8) = *(const short8*)(const void*)(Xs + i * 8);
        }
    }
}

// ---------------- CSR build ----------------
__global__ void hist_kernel(const int* __restrict__ ei, const int* __restrict__ flags,
                            int* __restrict__ counts, int* __restrict__ loff, int E) {
    int e = blockIdx.x * blockDim.x + threadIdx.x;
    if (e < E) {
        int d = flags[1] ? ei[2 * (size_t)E + 2 * e] : ei[(size_t)E + e];
        loff[e] = atomicAdd(&counts[d], 1);
    }
}

__global__ __launch_bounds__(256) void alloc_kernel(const int* __restrict__ counts,
                                                    float* __restrict__ dinv,
                                                    int* __restrict__ rowptr,
                                                    int* __restrict__ total, int N) {
    int n = blockIdx.x * blockDim.x + threadIdx.x;
    int lane = threadIdx.x & 63;
    int c = (n < N) ? counts[n] : 0;
    if (n < N) {
        int d = (c < 1) ? 1 : c;
        dinv[n] = rsqrtf((float)d);
    }
    int incl = c;
#pragma unroll
    for (int off = 1; off < 64; off <<= 1) {
        int v = __shfl_up(incl, off, 64);
        if (lane >= off) incl += v;
    }
    int wavetot = __shfl(incl, 63, 64);
    int base = 0;
    if (lane == 0) base = atomicAdd(total, wavetot);
    base = __shfl(base, 0, 64);
    if (n < N) rowptr[n] = base + incl - c;
}

__global__ void fill_kernel(const int* __restrict__ ei, const int* __restrict__ flags,
                            const float* __restrict__ dinv, const int* __restrict__ rowptr,
                            const int* __restrict__ loff, int2* __restrict__ edgedat, int E) {
    int e = blockIdx.x * blockDim.x + threadIdx.x;
    if (e < E) {
        int s, d;
        if (flags[1]) {
            s = ei[2 * e];
            d = ei[2 * (size_t)E + 2 * e];
        } else {
            s = ei[e];
            d = ei[(size_t)E + e];
        }
        int pos = rowptr[d] + loff[e];
        float wt = dinv[s] * dinv[d];
        edgedat[pos] = make_int2(s, __float_as_int(wt));
    }
}

// ---------------- W staging: bt[n][k] = W[k][n], LDB=136 ----------------
template <int FOUT>
static __device__ inline void stage_w(const void* __restrict__ Wraw, int in_fp32,
                                      unsigned short* __restrict__ bt, int tid) {
    constexpr int K = 128;
    constexpr int LDB = K + 8;
    constexpr int TOT4 = K * FOUT / 4;
    if (in_fp32) {
        const float* Wf = (const float*)Wraw;
        for (int i = tid; i < TOT4; i += 256) {
            int idx = i * 4;
            int k = idx / FOUT;
            int n = idx & (FOUT - 1);
            float4 v = *(const float4*)(const void*)(Wf + idx);
            bt[(n + 0) * LDB + k] = f2bf(v.x);
            bt[(n + 1) * LDB + k] = f2bf(v.y);
            bt[(n + 2) * LDB + k] = f2bf(v.z);
            bt[(n + 3) * LDB + k] = f2bf(v.w);
        }
    } else {
        const unsigned short* Ws = (const unsigned short*)Wraw;
        for (int i = tid; i < TOT4; i += 256) {
            int idx = i * 4;
            int k = idx / FOUT;
            int n = idx & (FOUT - 1);
            short4v v = *(const short4v*)(const void*)(Ws + idx);
#pragma unroll
            for (int j = 0; j < 4; j++) bt[(n + j) * LDB + k] = ((const unsigned short*)&v)[j];
        }
    }
}

// ---------------- Fused layer: h_out = relu( (A . Hprev) @ W ) [ @ W3 if FUSE3 ] ----------------
// Block = 256 threads = 4 waves, 64 nodes (16 per wave).
// Phase 1: wave aggregates its 16 nodes (grouped gather: 4 groups x 16 lanes, short8 = 8 feats),
//          writes bf16 rows into the agg LDS tile (wave-local rows -> no cross-wave sync).
// Phase 2: per-wave MFMA over its own 16 rows with W staged in LDS.
// FUSE3: relu(C) goes back to the wave's own agg rows, second MFMA with W3 -> z3 (64-wide, no relu).

template <bool FUSE3>
__global__ __launch_bounds__(256) void fused_layer_kernel(const unsigned short* __restrict__ Hprev,
                                                          const void* __restrict__ Wraw,
                                                          const void* __restrict__ W3raw,
                                                          const int2* __restrict__ edgedat,
                                                          const int* __restrict__ rowptr,
                                                          const int* __restrict__ counts,
                                                          const int* __restrict__ flags,
                                                          unsigned short* __restrict__ out,
                                                          int N) {
    constexpr int LDB = 136;
    __shared__ __align__(16) unsigned short btW[128 * LDB];                    // 34816 B
    __shared__ __align__(16) unsigned short agg[64 * LDB];                     // 17408 B
    __shared__ __align__(16) unsigned short btW3[FUSE3 ? 64 * LDB : 8];       // 17408 B if used

    const int tid = threadIdx.x;
    const int in_fp32 = flags[0];

    stage_w<128>(Wraw, in_fp32, btW, tid);
    if constexpr (FUSE3) stage_w<64>(W3raw, in_fp32, btW3, tid);
    __syncthreads();  // only W tiles need cross-wave visibility

    const int wave = tid >> 6;
    const int lane = tid & 63;
    const int grp = lane >> 4;   // 4 groups of 16 lanes
    const int gl = lane & 15;    // feature chunk gl*8 .. gl*8+7

    // ---- Phase 1: aggregation, 16 nodes per wave ----
    for (int i = 0; i < 16; i++) {
        int node = blockIdx.x * 64 + wave * 16 + i;
        int start = 0, len = 0;
        if (node < N) {
            start = rowptr[node];
            len = counts[node];
        }
        start = __builtin_amdgcn_readfirstlane(start);
        len = __builtin_amdgcn_readfirstlane(len);
        const int2* ep = edgedat + start;

        float acc[8];
#pragma unroll
        for (int u = 0; u < 8; u++) acc[u] = 0.f;

        int j = 0;
        for (; j + 8 <= len; j += 8) {
            int2 e0 = ep[j + grp];
            int2 e1 = ep[j + 4 + grp];
            short8 h0 = *(const short8*)(const void*)(Hprev + (size_t)e0.x * 128 + gl * 8);
            short8 h1 = *(const short8*)(const void*)(Hprev + (size_t)e1.x * 128 + gl * 8);
            float w0 = __int_as_float(e0.y);
            float w1 = __int_as_float(e1.y);
#pragma unroll
            for (int u = 0; u < 8; u++) acc[u] += w0 * bf2f((unsigned short)h0[u]);
#pragma unroll
            for (int u = 0; u < 8; u++) acc[u] += w1 * bf2f((unsigned short)h1[u]);
        }
        for (; j + 4 <= len; j += 4) {
            int2 e = ep[j + grp];
            short8 h = *(const short8*)(const void*)(Hprev + (size_t)e.x * 128 + gl * 8);
            float w = __int_as_float(e.y);
#pragma unroll
            for (int u = 0; u < 8; u++) acc[u] += w * bf2f((unsigned short)h[u]);
        }
        int rem = len - j;
        if (grp < rem) {
            int2 e = ep[j + grp];
            short8 h = *(const short8*)(const void*)(Hprev + (size_t)e.x * 128 + gl * 8);
            float w = __int_as_float(e.y);
#pragma unroll
            for (int u = 0; u < 8; u++) acc[u] += w * bf2f((unsigned short)h[u]);
        }

#pragma unroll
        for (int u = 0; u < 8; u++) {
            acc[u] += __shfl_xor(acc[u], 16, 64);
            acc[u] += __shfl_xor(acc[u], 32, 64);
        }

        if (grp == 0) {
            short8 o;
#pragma unroll
            for (int u = 0; u < 8; u++) o[u] = (short)f2bf(acc[u]);
            *(short8*)(void*)(&agg[(wave * 16 + i) * LDB + gl * 8]) = o;
        }
    }

    // ---- Phase 2: per-wave MFMA (A rows are wave-local; no barrier needed) ----
    const int quad = lane >> 4;
    const int r16 = lane & 15;

    short8 afrag[4];
#pragma unroll
    for (int kk = 0; kk < 4; kk++)
        afrag[kk] = *(const short8*)(const void*)(&agg[(wave * 16 + r16) * LDB + kk * 32 + quad * 8]);

    f32x4 acc2[8];
#pragma unroll
    for (int nt = 0; nt < 8; nt++) acc2[nt] = (f32x4){0.f, 0.f, 0.f, 0.f};

#pragma unroll
    for (int kk = 0; kk < 4; kk++) {
#pragma unroll
        for (int nt = 0; nt < 8; nt++) {
            short8 b = *(const short8*)(const void*)(&btW[(nt * 16 + r16) * LDB + kk * 32 + quad * 8]);
            acc2[nt] = __builtin_amdgcn_mfma_f32_16x16x32_bf16(afrag[kk], b, acc2[nt], 0, 0, 0);
        }
    }

    if constexpr (!FUSE3) {
        // relu + pack pairs + store h (node-major [N][128] bf16)
#pragma unroll
        for (int nt = 0; nt < 8; nt++) {
#pragma unroll
            for (int r = 0; r < 4; r++) {
                float v = fmaxf(acc2[nt][r], 0.f);
                float o = __shfl_xor(v, 1, 64);
                int row = blockIdx.x * 64 + wave * 16 + quad * 4 + r;
                if (((lane & 1) == 0) && row < N) {
                    __hip_bfloat162 pk;
                    pk.x = __float2bfloat16(v);
                    pk.y = __float2bfloat16(o);
                    *(__hip_bfloat162*)(out + (size_t)row * 128 + nt * 16 + r16) = pk;
                }
            }
        }
    } else {
        // relu(C) -> back into this wave's own agg rows (bf16)
#pragma unroll
        for (int nt = 0; nt < 8; nt++) {
#pragma unroll
            for (int r = 0; r < 4; r++) {
                float v = fmaxf(acc2[nt][r], 0.f);
                float o = __shfl_xor(v, 1, 64);
                if ((lane & 1) == 0) {
                    __hip_bfloat162 pk;
                    pk.x = __float2bfloat16(v);
                    pk.y = __float2bfloat16(o);
                    *(__hip_bfloat162*)(&agg[(wave * 16 + quad * 4 + r) * LDB + nt * 16 + r16]) = pk;
                }
            }
        }
        // second MFMA: z3 = h2_tile @ W3  (64-wide, NO relu)
        short8 afrag3[4];
#pragma unroll
        for (int kk = 0; kk < 4; kk++)
            afrag3[kk] = *(const short8*)(const void*)(&agg[(wave * 16 + r16) * LDB + kk * 32 + quad * 8]);

        f32x4 acc3[4];
#pragma unroll
        for (int nt = 0; nt < 4; nt++) acc3[nt] = (f32x4){0.f, 0.f, 0.f, 0.f};
#pragma unroll
        for (int kk = 0; kk < 4; kk++) {
#pragma unroll
            for (int nt = 0; nt < 4; nt++) {
                short8 b = *(const short8*)(const void*)(&btW3[(nt * 16 + r16) * LDB + kk * 32 + quad * 8]);
                acc3[nt] = __builtin_amdgcn_mfma_f32_16x16x32_bf16(afrag3[kk], b, acc3[nt], 0, 0, 0);
            }
        }
#pragma unroll
        for (int nt = 0; nt < 4; nt++) {
#pragma unroll
            for (int r = 0; r < 4; r++) {
                float v = acc3[nt][r];
                float o = __shfl_xor(v, 1, 64);
                int row = blockIdx.x * 64 + wave * 16 + quad * 4 + r;
                if (((lane & 1) == 0) && row < N) {
                    __hip_bfloat162 pk;
                    pk.x = __float2bfloat16(v);
                    pk.y = __float2bfloat16(o);
                    *(__hip_bfloat162*)(out + (size_t)row * 64 + nt * 16 + r16) = pk;
                }
            }
        }
    }
}

// ---------------- SpMM F=64 + relu + softmax (node-major z3 input) ----------------
__global__ __launch_bounds__(256) void spmm64_softmax_kernel(const int2* __restrict__ edgedat,
                                                             const int* __restrict__ rowptr,
                                                             const int* __restrict__ counts,
                                                             const unsigned short* __restrict__ Hin,
                                                             const int* __restrict__ flags,
                                                             void* __restrict__ Out, int N) {
    int wid = (blockIdx.x * 256 + threadIdx.x) >> 6;
    if (wid >= N) return;
    int lane = threadIdx.x & 63;
    int grp = lane >> 3;
    int gl = lane & 7;
    int n = __builtin_amdgcn_readfirstlane(wid);
    int start = __builtin_amdgcn_readfirstlane(rowptr[n]);
    int len = __builtin_amdgcn_readfirstlane(counts[n]);
    const int2* ep = edgedat + start;

    float acc[8];
#pragma unroll
    for (int u = 0; u < 8; u++) acc[u] = 0.f;

    int j = 0;
    for (; j + 16 <= len; j += 16) {
        int2 e0 = ep[j + grp];
        int2 e1 = ep[j + 8 + grp];
        short8 h0 = *(const short8*)(const void*)(Hin + (size_t)e0.x * 64 + gl * 8);
        short8 h1 = *(const short8*)(const void*)(Hin + (size_t)e1.x * 64 + gl * 8);
        float w0 = __int_as_float(e0.y);
        float w1 = __int_as_float(e1.y);
#pragma unroll
        for (int u = 0; u < 8; u++) acc[u] += w0 * bf2f((unsigned short)h0[u]);
#pragma unroll
        for (int u = 0; u < 8; u++) acc[u] += w1 * bf2f((unsigned short)h1[u]);
    }
    for (; j + 8 <= len; j += 8) {
        int2 e = ep[j + grp];
        short8 h = *(const short8*)(const void*)(Hin + (size_t)e.x * 64 + gl * 8);
        float w = __int_as_float(e.y);
#pragma unroll
        for (int u = 0; u < 8; u++) acc[u] += w * bf2f((unsigned short)h[u]);
    }
    int rem = len - j;
    if (grp < rem) {
        int2 e = ep[j + grp];
        short8 h = *(const short8*)(const void*)(Hin + (size_t)e.x * 64 + gl * 8);
        float w = __int_as_float(e.y);
#pragma unroll
        for (int u = 0; u < 8; u++) acc[u] += w * bf2f((unsigned short)h[u]);
    }

#pragma unroll
    for (int u = 0; u < 8; u++) {
        acc[u] += __shfl_xor(acc[u], 8, 64);
        acc[u] += __shfl_xor(acc[u], 16, 64);
        acc[u] += __shfl_xor(acc[u], 32, 64);
    }

#pragma unroll
    for (int u = 0; u < 8; u++) acc[u] = fmaxf(acc[u], 0.f);

    float m = acc[0];
#pragma unroll
    for (int u = 1; u < 8; u++) m = fmaxf(m, acc[u]);
#pragma unroll
    for (int off = 1; off < 8; off <<= 1) m = fmaxf(m, __shfl_xor(m, off, 64));

    float ex[8];
    float s = 0.f;
#pragma unroll
    for (int u = 0; u < 8; u++) {
        ex[u] = __expf(acc[u] - m);
        s += ex[u];
    }
#pragma unroll
    for (int off = 1; off < 8; off <<= 1) s += __shfl_xor(s, off, 64);
    float inv = 1.0f / s;

    if (grp == 0) {
        if (flags[0]) {
            float* op = (float*)Out + (size_t)n * 64 + gl * 8;
            float4 v0, v1;
            v0.x = ex[0] * inv; v0.y = ex[1] * inv; v0.z = ex[2] * inv; v0.w = ex[3] * inv;
            v1.x = ex[4] * inv; v1.y = ex[5] * inv; v1.z = ex[6] * inv; v1.w = ex[7] * inv;
            *(float4*)(void*)op = v0;
            *(float4*)(void*)(op + 4) = v1;
        } else {
            short8 o;
#pragma unroll
            for (int u = 0; u < 8; u++) o[u] = (short)f2bf(ex[u] * inv);
            *(short8*)(void*)((unsigned short*)Out + (size_t)n * 64 + gl * 8) = o;
        }
    }
}

// ---------------- launch ----------------

extern "C" void kernel_launch(void* const* d_in, const int* in_sizes, int n_in,
                              void* d_out, int out_size, void* d_ws, size_t ws_size,
                              hipStream_t stream) {
    const void* X  = d_in[0];                       // [N,128] bf16 or fp32
    const int*  ei = (const int*)d_in[1];           // [2,E] int32 or int64
    const void* W1 = d_in[2];                       // [128,128]
    const void* W2 = d_in[3];                       // [128,128]
    const void* W3 = d_in[4];                       // [128,64]

    const int N = in_sizes[0] / 128;   // 50000
    const int E = in_sizes[1] / 2;     // 800000

    char* ws = (char*)d_ws;
    size_t off = 0;
    int* counts = (int*)(ws + off);   off += ws_align((size_t)N * 4);
    int* total  = (int*)(ws + off);   off += ws_align(64);
    const size_t zero_bytes = off;    // counts + total need zeroing
    int* flags    = (int*)(ws + off);   off += ws_align(64);
    int* rowptr   = (int*)(ws + off);   off += ws_align((size_t)N * 4);
    float* dinv   = (float*)(ws + off); off += ws_align((size_t)N * 4);
    int* loff     = (int*)(ws + off);   off += ws_align((size_t)E * 4);
    int2* edgedat = (int2*)(ws + off);  off += ws_align((size_t)E * 8);
    unsigned short* Xb = (unsigned short*)(ws + off); off += ws_align((size_t)N * 128 * 2);
    unsigned short* H1 = (unsigned short*)(ws + off); off += ws_align((size_t)N * 128 * 2);
    unsigned short* Z3 = (unsigned short*)(ws + off); off += ws_align((size_t)N * 64 * 2);

    hipMemsetAsync(d_ws, 0, zero_bytes, stream);

    sniff_kernel<<<1, 64, 0, stream>>>((const unsigned short*)W1, (const unsigned int*)ei, flags);

    long long total8 = (long long)N * 16;  // N*128/8
    int cblocks = (int)((total8 + 255) / 256);
    if (cblocks > 2048) cblocks = 2048;
    xconv_kernel<<<cblocks, 256, 0, stream>>>(X, flags, Xb, total8);

    hist_kernel<<<(E + 255) / 256, 256, 0, stream>>>(ei, flags, counts, loff, E);
    alloc_kernel<<<(N + 255) / 256, 256, 0, stream>>>(counts, dinv, rowptr, total, N);
    fill_kernel<<<(E + 255) / 256, 256, 0, stream>>>(ei, flags, dinv, rowptr, loff, edgedat, E);

    const int fblocks = (N + 63) / 64;
    const int sblocks = (N * 64 + 255) / 256;

    // layer 1: H1 = relu( agg(Xb) @ W1 )
    fused_layer_kernel<false><<<fblocks, 256, 0, stream>>>(Xb, W1, nullptr, edgedat, rowptr,
                                                           counts, flags, H1, N);
    // layers 2+3 GEMM: Z3 = relu( agg(H1) @ W2 ) @ W3
    fused_layer_kernel<true><<<fblocks, 256, 0, stream>>>(H1, W2, W3, edgedat, rowptr,
                                                          counts, flags, Z3, N);
    // final aggregation + relu + softmax
    spmm64_softmax_kernel<<<sblocks, 256, 0, stream>>>(edgedat, rowptr, counts, Z3, flags, d_out, N);
}

// Round 5
// 278.115 us; speedup vs baseline: 1.3406x; 1.3406x over previous
//
#include <hip/hip_runtime.h>
#include <hip/hip_bf16.h>

typedef __attribute__((ext_vector_type(8))) short short8;
typedef __attribute__((ext_vector_type(4))) float f32x4;

static inline size_t ws_align(size_t x) { return (x + 511) & ~((size_t)511); }

static __device__ inline unsigned short f2bf(float f) {
    __hip_bfloat16 h = __float2bfloat16(f);
    return __builtin_bit_cast(unsigned short, h);
}

static __device__ inline float bf2f(unsigned short u) {
    unsigned int x = ((unsigned int)u) << 16;
    return __builtin_bit_cast(float, x);
}

// ---------------- dtype sniffing ----------------
// flags[0] = 1 if float inputs are fp32 (else bf16)
// flags[1] = 1 if edge_index is int64 (else int32)
__global__ void sniff_kernel(const unsigned short* __restrict__ w1,
                             const unsigned int* __restrict__ ei,
                             int* __restrict__ flags) {
    int i = threadIdx.x;  // 64 threads
    unsigned e = (w1[2 * i] >> 7) & 0xFF;
    unsigned long long m1 = __ballot(e >= 100 && e <= 130);
    unsigned long long m2 = __ballot(ei[2 * i + 1] == 0u);
    if (i == 0) {
        flags[0] = (__popcll(m1) < 48) ? 1 : 0;
        flags[1] = (__popcll(m2) >= 48) ? 1 : 0;
    }
}

// ---------------- W pre-transpose: Wt[n][k] = W[k][n], bf16, global ----------------
// W1/W2: 128x128, W3: 128x64. Total 40960 elements; grid 160 x 256 covers exactly.
__global__ __launch_bounds__(256) void wconv_kernel(const void* __restrict__ W1raw,
                                                    const void* __restrict__ W2raw,
                                                    const void* __restrict__ W3raw,
                                                    const int* __restrict__ flags,
                                                    unsigned short* __restrict__ wt1,
                                                    unsigned short* __restrict__ wt2,
                                                    unsigned short* __restrict__ wt3) {
    int idx = blockIdx.x * 256 + threadIdx.x;
    int in_fp32 = flags[0];
    const void* src;
    unsigned short* dst;
    int e, fout;
    if (idx < 16384) {
        src = W1raw; dst = wt1; e = idx; fout = 128;
    } else if (idx < 32768) {
        src = W2raw; dst = wt2; e = idx - 16384; fout = 128;
    } else if (idx < 40960) {
        src = W3raw; dst = wt3; e = idx - 32768; fout = 64;
    } else {
        return;
    }
    int n = e & (fout - 1);
    int k = e / fout;
    unsigned short v;
    if (in_fp32) v = f2bf(((const float*)src)[e]);
    else         v = ((const unsigned short*)src)[e];
    dst[n * 128 + k] = v;
}

// ---------------- CSR build ----------------
__global__ void hist_kernel(const int* __restrict__ ei, const int* __restrict__ flags,
                            int* __restrict__ counts, int* __restrict__ loff, int E) {
    int e = blockIdx.x * blockDim.x + threadIdx.x;
    if (e < E) {
        int d = flags[1] ? ei[2 * (size_t)E + 2 * e] : ei[(size_t)E + e];
        loff[e] = atomicAdd(&counts[d], 1);
    }
}

__global__ __launch_bounds__(256) void alloc_kernel(const int* __restrict__ counts,
                                                    float* __restrict__ dinv,
                                                    int* __restrict__ rowptr,
                                                    int* __restrict__ total, int N) {
    int n = blockIdx.x * blockDim.x + threadIdx.x;
    int lane = threadIdx.x & 63;
    int c = (n < N) ? counts[n] : 0;
    if (n < N) {
        int d = (c < 1) ? 1 : c;
        dinv[n] = rsqrtf((float)d);
    }
    int incl = c;
#pragma unroll
    for (int off = 1; off < 64; off <<= 1) {
        int v = __shfl_up(incl, off, 64);
        if (lane >= off) incl += v;
    }
    int wavetot = __shfl(incl, 63, 64);
    int base = 0;
    if (lane == 0) base = atomicAdd(total, wavetot);
    base = __shfl(base, 0, 64);
    if (n < N) rowptr[n] = base + incl - c;
}

__global__ void fill_kernel(const int* __restrict__ ei, const int* __restrict__ flags,
                            const float* __restrict__ dinv, const int* __restrict__ rowptr,
                            const int* __restrict__ loff, int2* __restrict__ edgedat, int E) {
    int e = blockIdx.x * blockDim.x + threadIdx.x;
    if (e < E) {
        int s, d;
        if (flags[1]) {
            s = ei[2 * e];
            d = ei[2 * (size_t)E + 2 * e];
        } else {
            s = ei[e];
            d = ei[(size_t)E + e];
        }
        int pos = rowptr[d] + loff[e];
        float wt = dinv[s] * dinv[d];
        edgedat[pos] = make_int2(s, __float_as_int(wt));
    }
}

// ---------------- GEMM: out[N x FOUT] = A[N x 128] @ W[128 x FOUT], bf16 MFMA ----------------
// B read directly from pre-transposed global Wt (bf16, L2-resident). No LDS, no barrier.
// 256 threads = 4 waves; each wave computes 2 row-tiles of 16 -> 128 rows/block.

template <int FOUT>
__global__ __launch_bounds__(256) void gemm_kernel(const void* __restrict__ Araw, int a_follows,
                                                   const unsigned short* __restrict__ wt,
                                                   const int* __restrict__ flags,
                                                   unsigned short* __restrict__ out, int Nrows) {
    constexpr int K = 128;
    constexpr int NT = FOUT / 16;

    const int tid = threadIdx.x;
    const int in_fp32 = flags[0];
    const int a_fp32 = a_follows & in_fp32;

    const int wave = tid >> 6;
    const int lane = tid & 63;
    const int quad = lane >> 4;
    const int r16 = lane & 15;

    short8 afrag[2][4];
#pragma unroll
    for (int t = 0; t < 2; t++) {
        int arow = blockIdx.x * 128 + t * 64 + wave * 16 + r16;
        if (arow > Nrows - 1) arow = Nrows - 1;
        if (a_fp32) {
            const float* Ap = (const float*)Araw + (size_t)arow * K + quad * 8;
#pragma unroll
            for (int kk = 0; kk < 4; kk++) {
                float4 f0 = *(const float4*)(const void*)(Ap + kk * 32);
                float4 f1 = *(const float4*)(const void*)(Ap + kk * 32 + 4);
                short8 r;
                r[0] = (short)f2bf(f0.x); r[1] = (short)f2bf(f0.y);
                r[2] = (short)f2bf(f0.z); r[3] = (short)f2bf(f0.w);
                r[4] = (short)f2bf(f1.x); r[5] = (short)f2bf(f1.y);
                r[6] = (short)f2bf(f1.z); r[7] = (short)f2bf(f1.w);
                afrag[t][kk] = r;
            }
        } else {
            const unsigned short* Ap = (const unsigned short*)Araw + (size_t)arow * K + quad * 8;
#pragma unroll
            for (int kk = 0; kk < 4; kk++) afrag[t][kk] = *(const short8*)(const void*)(Ap + kk * 32);
        }
    }

    f32x4 acc[2][NT];
#pragma unroll
    for (int t = 0; t < 2; t++)
#pragma unroll
        for (int nt = 0; nt < NT; nt++) acc[t][nt] = (f32x4){0.f, 0.f, 0.f, 0.f};

#pragma unroll
    for (int kk = 0; kk < 4; kk++) {
#pragma unroll
        for (int nt = 0; nt < NT; nt++) {
            short8 b = *(const short8*)(const void*)(wt + (size_t)(nt * 16 + r16) * 128 + kk * 32 + quad * 8);
#pragma unroll
            for (int t = 0; t < 2; t++)
                acc[t][nt] = __builtin_amdgcn_mfma_f32_16x16x32_bf16(afrag[t][kk], b, acc[t][nt], 0, 0, 0);
        }
    }

    // C layout: col = lane&15, row = quad*4 + r. Pack col pairs via shfl_xor; even lanes store bf16x2.
#pragma unroll
    for (int t = 0; t < 2; t++) {
#pragma unroll
        for (int nt = 0; nt < NT; nt++) {
#pragma unroll
            for (int r = 0; r < 4; r++) {
                float v = acc[t][nt][r];
                float o = __shfl_xor(v, 1, 64);
                int row = blockIdx.x * 128 + t * 64 + wave * 16 + quad * 4 + r;
                if (((lane & 1) == 0) && row < Nrows) {
                    __hip_bfloat162 pk;
                    pk.x = __float2bfloat16(v);
                    pk.y = __float2bfloat16(o);
                    *(__hip_bfloat162*)(out + (size_t)row * FOUT + nt * 16 + r16) = pk;
                }
            }
        }
    }
}

// ---------------- SpMM: wave per node, 4 edges in flight (16-lane groups, 16B row slices) ----------------

__global__ __launch_bounds__(256) void spmm128_kernel(const int2* __restrict__ edgedat,
                                                      const int* __restrict__ rowptr,
                                                      const int* __restrict__ counts,
                                                      const unsigned short* __restrict__ Hin,
                                                      unsigned short* __restrict__ Hout, int N) {
    int wid = (blockIdx.x * 256 + threadIdx.x) >> 6;
    if (wid >= N) return;
    int lane = threadIdx.x & 63;
    int grp = lane >> 4;
    int gl = lane & 15;
    int n = __builtin_amdgcn_readfirstlane(wid);
    int start = __builtin_amdgcn_readfirstlane(rowptr[n]);
    int len = __builtin_amdgcn_readfirstlane(counts[n]);
    const int2* ep = edgedat + start;

    float acc[8];
#pragma unroll
    for (int u = 0; u < 8; u++) acc[u] = 0.f;

    int j = 0;
    for (; j + 8 <= len; j += 8) {
        int2 e0 = ep[j + grp];
        int2 e1 = ep[j + 4 + grp];
        short8 h0 = *(const short8*)(const void*)(Hin + (size_t)e0.x * 128 + gl * 8);
        short8 h1 = *(const short8*)(const void*)(Hin + (size_t)e1.x * 128 + gl * 8);
        float w0 = __int_as_float(e0.y);
        float w1 = __int_as_float(e1.y);
#pragma unroll
        for (int u = 0; u < 8; u++) acc[u] += w0 * bf2f((unsigned short)h0[u]);
#pragma unroll
        for (int u = 0; u < 8; u++) acc[u] += w1 * bf2f((unsigned short)h1[u]);
    }
    for (; j + 4 <= len; j += 4) {
        int2 e = ep[j + grp];
        short8 h = *(const short8*)(const void*)(Hin + (size_t)e.x * 128 + gl * 8);
        float w = __int_as_float(e.y);
#pragma unroll
        for (int u = 0; u < 8; u++) acc[u] += w * bf2f((unsigned short)h[u]);
    }
    int rem = len - j;
    if (grp < rem) {
        int2 e = ep[j + grp];
        short8 h = *(const short8*)(const void*)(Hin + (size_t)e.x * 128 + gl * 8);
        float w = __int_as_float(e.y);
#pragma unroll
        for (int u = 0; u < 8; u++) acc[u] += w * bf2f((unsigned short)h[u]);
    }

#pragma unroll
    for (int u = 0; u < 8; u++) {
        acc[u] += __shfl_xor(acc[u], 16, 64);
        acc[u] += __shfl_xor(acc[u], 32, 64);
    }

    if (grp == 0) {
        short8 o;
#pragma unroll
        for (int u = 0; u < 8; u++) o[u] = (short)f2bf(fmaxf(acc[u], 0.f));
        *(short8*)(void*)(Hout + (size_t)n * 128 + gl * 8) = o;
    }
}

// ---------------- SpMM F=64 + relu + softmax: 8 edges in flight (8-lane groups) ----------------

__global__ __launch_bounds__(256) void spmm64_softmax_kernel(const int2* __restrict__ edgedat,
                                                             const int* __restrict__ rowptr,
                                                             const int* __restrict__ counts,
                                                             const unsigned short* __restrict__ Hin,
                                                             const int* __restrict__ flags,
                                                             void* __restrict__ Out, int N) {
    int wid = (blockIdx.x * 256 + threadIdx.x) >> 6;
    if (wid >= N) return;
    int lane = threadIdx.x & 63;
    int grp = lane >> 3;
    int gl = lane & 7;
    int n = __builtin_amdgcn_readfirstlane(wid);
    int start = __builtin_amdgcn_readfirstlane(rowptr[n]);
    int len = __builtin_amdgcn_readfirstlane(counts[n]);
    const int2* ep = edgedat + start;

    float acc[8];
#pragma unroll
    for (int u = 0; u < 8; u++) acc[u] = 0.f;

    int j = 0;
    for (; j + 16 <= len; j += 16) {
        int2 e0 = ep[j + grp];
        int2 e1 = ep[j + 8 + grp];
        short8 h0 = *(const short8*)(const void*)(Hin + (size_t)e0.x * 64 + gl * 8);
        short8 h1 = *(const short8*)(const void*)(Hin + (size_t)e1.x * 64 + gl * 8);
        float w0 = __int_as_float(e0.y);
        float w1 = __int_as_float(e1.y);
#pragma unroll
        for (int u = 0; u < 8; u++) acc[u] += w0 * bf2f((unsigned short)h0[u]);
#pragma unroll
        for (int u = 0; u < 8; u++) acc[u] += w1 * bf2f((unsigned short)h1[u]);
    }
    for (; j + 8 <= len; j += 8) {
        int2 e = ep[j + grp];
        short8 h = *(const short8*)(const void*)(Hin + (size_t)e.x * 64 + gl * 8);
        float w = __int_as_float(e.y);
#pragma unroll
        for (int u = 0; u < 8; u++) acc[u] += w * bf2f((unsigned short)h[u]);
    }
    int rem = len - j;
    if (grp < rem) {
        int2 e = ep[j + grp];
        short8 h = *(const short8*)(const void*)(Hin + (size_t)e.x * 64 + gl * 8);
        float w = __int_as_float(e.y);
#pragma unroll
        for (int u = 0; u < 8; u++) acc[u] += w * bf2f((unsigned short)h[u]);
    }

#pragma unroll
    for (int u = 0; u < 8; u++) {
        acc[u] += __shfl_xor(acc[u], 8, 64);
        acc[u] += __shfl_xor(acc[u], 16, 64);
        acc[u] += __shfl_xor(acc[u], 32, 64);
    }

#pragma unroll
    for (int u = 0; u < 8; u++) acc[u] = fmaxf(acc[u], 0.f);

    float m = acc[0];
#pragma unroll
    for (int u = 1; u < 8; u++) m = fmaxf(m, acc[u]);
#pragma unroll
    for (int off = 1; off < 8; off <<= 1) m = fmaxf(m, __shfl_xor(m, off, 64));

    float ex[8];
    float s = 0.f;
#pragma unroll
    for (int u = 0; u < 8; u++) {
        ex[u] = __expf(acc[u] - m);
        s += ex[u];
    }
#pragma unroll
    for (int off = 1; off < 8; off <<= 1) s += __shfl_xor(s, off, 64);
    float inv = 1.0f / s;

    if (grp == 0) {
        if (flags[0]) {
            float* op = (float*)Out + (size_t)n * 64 + gl * 8;
            float4 v0, v1;
            v0.x = ex[0] * inv; v0.y = ex[1] * inv; v0.z = ex[2] * inv; v0.w = ex[3] * inv;
            v1.x = ex[4] * inv; v1.y = ex[5] * inv; v1.z = ex[6] * inv; v1.w = ex[7] * inv;
            *(float4*)(void*)op = v0;
            *(float4*)(void*)(op + 4) = v1;
        } else {
            short8 o;
#pragma unroll
            for (int u = 0; u < 8; u++) o[u] = (short)f2bf(ex[u] * inv);
            *(short8*)(void*)((unsigned short*)Out + (size_t)n * 64 + gl * 8) = o;
        }
    }
}

// ---------------- launch ----------------

extern "C" void kernel_launch(void* const* d_in, const int* in_sizes, int n_in,
                              void* d_out, int out_size, void* d_ws, size_t ws_size,
                              hipStream_t stream) {
    const void* X  = d_in[0];                       // [N,128] bf16 or fp32
    const int*  ei = (const int*)d_in[1];           // [2,E] int32 or int64
    const void* W1 = d_in[2];                       // [128,128]
    const void* W2 = d_in[3];                       // [128,128]
    const void* W3 = d_in[4];                       // [128,64]

    const int N = in_sizes[0] / 128;   // 50000
    const int E = in_sizes[1] / 2;     // 800000

    char* ws = (char*)d_ws;
    size_t off = 0;
    int* counts = (int*)(ws + off);   off += ws_align((size_t)N * 4);
    int* total  = (int*)(ws + off);   off += ws_align(64);
    const size_t zero_bytes = off;    // counts + total need zeroing
    int* flags    = (int*)(ws + off);   off += ws_align(64);
    int* rowptr   = (int*)(ws + off);   off += ws_align((size_t)N * 4);
    float* dinv   = (float*)(ws + off); off += ws_align((size_t)N * 4);
    int* loff     = (int*)(ws + off);   off += ws_align((size_t)E * 4);
    int2* edgedat = (int2*)(ws + off);  off += ws_align((size_t)E * 8);
    unsigned short* HA = (unsigned short*)(ws + off); off += ws_align((size_t)N * 128 * 2);
    unsigned short* HB = (unsigned short*)(ws + off); off += ws_align((size_t)N * 128 * 2);
    unsigned short* wt1 = (unsigned short*)(ws + off); off += ws_align(16384 * 2);
    unsigned short* wt2 = (unsigned short*)(ws + off); off += ws_align(16384 * 2);
    unsigned short* wt3 = (unsigned short*)(ws + off); off += ws_align(8192 * 2);

    hipMemsetAsync(d_ws, 0, zero_bytes, stream);

    sniff_kernel<<<1, 64, 0, stream>>>((const unsigned short*)W1, (const unsigned int*)ei, flags);
    wconv_kernel<<<160, 256, 0, stream>>>(W1, W2, W3, flags, wt1, wt2, wt3);
    hist_kernel<<<(E + 255) / 256, 256, 0, stream>>>(ei, flags, counts, loff, E);
    alloc_kernel<<<(N + 255) / 256, 256, 0, stream>>>(counts, dinv, rowptr, total, N);
    fill_kernel<<<(E + 255) / 256, 256, 0, stream>>>(ei, flags, dinv, rowptr, loff, edgedat, E);

    const int gblocks = (N + 127) / 128;
    const int sblocks = (N * 64 + 255) / 256;

    // layer 1: HA = X @ W1 ; HB = relu(A_norm HA)
    gemm_kernel<128><<<gblocks, 256, 0, stream>>>(X, 1, wt1, flags, HA, N);
    spmm128_kernel<<<sblocks, 256, 0, stream>>>(edgedat, rowptr, counts, HA, HB, N);
    // layer 2
    gemm_kernel<128><<<gblocks, 256, 0, stream>>>(HB, 0, wt2, flags, HA, N);
    spmm128_kernel<<<sblocks, 256, 0, stream>>>(edgedat, rowptr, counts, HA, HB, N);
    // layer 3 (F_out = 64) + relu + softmax
    gemm_kernel<64><<<gblocks, 256, 0, stream>>>(HB, 0, wt3, flags, HA, N);
    spmm64_softmax_kernel<<<sblocks, 256, 0, stream>>>(edgedat, rowptr, counts, HA, flags, d_out, N);
}

// Round 6
// 255.074 us; speedup vs baseline: 1.4617x; 1.0903x over previous
//
#include <hip/hip_runtime.h>
#include <hip/hip_bf16.h>

typedef __attribute__((ext_vector_type(8))) short short8;
typedef __attribute__((ext_vector_type(4))) short short4v;
typedef __attribute__((ext_vector_type(4))) float f32x4;

static inline size_t ws_align(size_t x) { return (x + 511) & ~((size_t)511); }

static __device__ inline unsigned short f2bf(float f) {
    __hip_bfloat16 h = __float2bfloat16(f);
    return __builtin_bit_cast(unsigned short, h);
}

static __device__ inline float bf2f(unsigned short u) {
    unsigned int x = ((unsigned int)u) << 16;
    return __builtin_bit_cast(float, x);
}

// ---------------- K1: gemm1 (X @ W1, LDS-staged) || hist, fused ----------------
// Blocks [0, gblocks): gemm1. Blocks [gblocks, gblocks+hblocks): hist + flag write.
// dtype flags computed wave-locally via ballot (no cross-block dependency).

__global__ __launch_bounds__(256) void gemm1_hist_kernel(const void* __restrict__ Araw,
                                                         const unsigned short* __restrict__ w1s,
                                                         const int* __restrict__ ei,
                                                         int* __restrict__ counts,
                                                         int* __restrict__ loff,
                                                         int* __restrict__ flags,
                                                         unsigned short* __restrict__ out,
                                                         int Nrows, int E, int gblocks) {
    constexpr int K = 128;
    constexpr int FOUT = 128;
    constexpr int NT = FOUT / 16;
    constexpr int LDB = K + 8;
    __shared__ __align__(16) unsigned short bt[FOUT * LDB];

    const int tid = threadIdx.x;
    const int lane = tid & 63;

    // wave-local dtype sniff (uniform across waves; cheap, L2-hot)
    unsigned ew = (w1s[2 * lane] >> 7) & 0xFF;
    unsigned long long m1 = __ballot(ew >= 100 && ew <= 130);
    const int in_fp32 = (__popcll(m1) < 48) ? 1 : 0;
    unsigned long long m2 = __ballot(((const unsigned int*)ei)[2 * lane + 1] == 0u);
    const int ei64 = (__popcll(m2) >= 48) ? 1 : 0;

    if (blockIdx.x >= gblocks) {
        // ---- hist part ----
        if (blockIdx.x == gblocks && tid == 0) {
            flags[0] = in_fp32;
            flags[1] = ei64;
        }
        int e = (blockIdx.x - gblocks) * 256 + tid;
        if (e < E) {
            int d = ei64 ? ei[2 * (size_t)E + 2 * e] : ei[(size_t)E + e];
            loff[e] = atomicAdd(&counts[d], 1);
        }
        return;
    }

    // ---- gemm1 part: stage W1 -> bt[n][k] ----
    constexpr int TOT4 = K * FOUT / 4;
    if (in_fp32) {
        const float* Wf = (const float*)(const void*)w1s;
        for (int i = tid; i < TOT4; i += 256) {
            int idx = i * 4;
            int k = idx / FOUT;
            int n = idx & (FOUT - 1);
            float4 v = *(const float4*)(const void*)(Wf + idx);
            bt[(n + 0) * LDB + k] = f2bf(v.x);
            bt[(n + 1) * LDB + k] = f2bf(v.y);
            bt[(n + 2) * LDB + k] = f2bf(v.z);
            bt[(n + 3) * LDB + k] = f2bf(v.w);
        }
    } else {
        for (int i = tid; i < TOT4; i += 256) {
            int idx = i * 4;
            int k = idx / FOUT;
            int n = idx & (FOUT - 1);
            short4v v = *(const short4v*)(const void*)(w1s + idx);
#pragma unroll
            for (int j = 0; j < 4; j++) bt[(n + j) * LDB + k] = ((const unsigned short*)&v)[j];
        }
    }

    const int wave = tid >> 6;
    const int quad = lane >> 4;
    const int r16 = lane & 15;

    short8 afrag[2][4];
#pragma unroll
    for (int t = 0; t < 2; t++) {
        int arow = blockIdx.x * 128 + t * 64 + wave * 16 + r16;
        if (arow > Nrows - 1) arow = Nrows - 1;
        if (in_fp32) {
            const float* Ap = (const float*)Araw + (size_t)arow * K + quad * 8;
#pragma unroll
            for (int kk = 0; kk < 4; kk++) {
                float4 f0 = *(const float4*)(const void*)(Ap + kk * 32);
                float4 f1 = *(const float4*)(const void*)(Ap + kk * 32 + 4);
                short8 r;
                r[0] = (short)f2bf(f0.x); r[1] = (short)f2bf(f0.y);
                r[2] = (short)f2bf(f0.z); r[3] = (short)f2bf(f0.w);
                r[4] = (short)f2bf(f1.x); r[5] = (short)f2bf(f1.y);
                r[6] = (short)f2bf(f1.z); r[7] = (short)f2bf(f1.w);
                afrag[t][kk] = r;
            }
        } else {
            const unsigned short* Ap = (const unsigned short*)Araw + (size_t)arow * K + quad * 8;
#pragma unroll
            for (int kk = 0; kk < 4; kk++) afrag[t][kk] = *(const short8*)(const void*)(Ap + kk * 32);
        }
    }

    __syncthreads();

    f32x4 acc[2][NT];
#pragma unroll
    for (int t = 0; t < 2; t++)
#pragma unroll
        for (int nt = 0; nt < NT; nt++) acc[t][nt] = (f32x4){0.f, 0.f, 0.f, 0.f};

#pragma unroll
    for (int kk = 0; kk < 4; kk++) {
#pragma unroll
        for (int nt = 0; nt < NT; nt++) {
            short8 b = *(const short8*)(const void*)(&bt[(nt * 16 + r16) * LDB + kk * 32 + quad * 8]);
#pragma unroll
            for (int t = 0; t < 2; t++)
                acc[t][nt] = __builtin_amdgcn_mfma_f32_16x16x32_bf16(afrag[t][kk], b, acc[t][nt], 0, 0, 0);
        }
    }

#pragma unroll
    for (int t = 0; t < 2; t++) {
#pragma unroll
        for (int nt = 0; nt < NT; nt++) {
#pragma unroll
            for (int r = 0; r < 4; r++) {
                float v = acc[t][nt][r];
                float o = __shfl_xor(v, 1, 64);
                int row = blockIdx.x * 128 + t * 64 + wave * 16 + quad * 4 + r;
                if (((lane & 1) == 0) && row < Nrows) {
                    __hip_bfloat162 pk;
                    pk.x = __float2bfloat16(v);
                    pk.y = __float2bfloat16(o);
                    *(__hip_bfloat162*)(out + (size_t)row * FOUT + nt * 16 + r16) = pk;
                }
            }
        }
    }
}

// ---------------- CSR build (alloc + fill) ----------------

__global__ __launch_bounds__(256) void alloc_kernel(const int* __restrict__ counts,
                                                    float* __restrict__ dinv,
                                                    int* __restrict__ rowptr,
                                                    int* __restrict__ total, int N) {
    int n = blockIdx.x * blockDim.x + threadIdx.x;
    int lane = threadIdx.x & 63;
    int c = (n < N) ? counts[n] : 0;
    if (n < N) {
        int d = (c < 1) ? 1 : c;
        dinv[n] = rsqrtf((float)d);
    }
    int incl = c;
#pragma unroll
    for (int off = 1; off < 64; off <<= 1) {
        int v = __shfl_up(incl, off, 64);
        if (lane >= off) incl += v;
    }
    int wavetot = __shfl(incl, 63, 64);
    int base = 0;
    if (lane == 0) base = atomicAdd(total, wavetot);
    base = __shfl(base, 0, 64);
    if (n < N) rowptr[n] = base + incl - c;
}

__global__ void fill_kernel(const int* __restrict__ ei, const int* __restrict__ flags,
                            const float* __restrict__ dinv, const int* __restrict__ rowptr,
                            const int* __restrict__ loff, int2* __restrict__ edgedat, int E) {
    int e = blockIdx.x * blockDim.x + threadIdx.x;
    if (e < E) {
        int s, d;
        if (flags[1]) {
            s = ei[2 * e];
            d = ei[2 * (size_t)E + 2 * e];
        } else {
            s = ei[e];
            d = ei[(size_t)E + e];
        }
        int pos = rowptr[d] + loff[e];
        float wt = dinv[s] * dinv[d];
        edgedat[pos] = make_int2(s, __float_as_int(wt));
    }
}

// ---------------- GEMM (layers 2,3): out[N x FOUT] = A[N x 128] @ W, LDS-staged W ----------------

template <int FOUT>
__global__ __launch_bounds__(256) void gemm_kernel(const void* __restrict__ Araw,
                                                   const void* __restrict__ Wraw,
                                                   const int* __restrict__ flags,
                                                   unsigned short* __restrict__ out, int Nrows) {
    constexpr int K = 128;
    constexpr int NT = FOUT / 16;
    constexpr int LDB = K + 8;
    __shared__ __align__(16) unsigned short bt[FOUT * LDB];

    const int tid = threadIdx.x;
    const int in_fp32 = flags[0];

    constexpr int TOT4 = K * FOUT / 4;
    if (in_fp32) {
        const float* Wf = (const float*)Wraw;
        for (int i = tid; i < TOT4; i += 256) {
            int idx = i * 4;
            int k = idx / FOUT;
            int n = idx & (FOUT - 1);
            float4 v = *(const float4*)(const void*)(Wf + idx);
            bt[(n + 0) * LDB + k] = f2bf(v.x);
            bt[(n + 1) * LDB + k] = f2bf(v.y);
            bt[(n + 2) * LDB + k] = f2bf(v.z);
            bt[(n + 3) * LDB + k] = f2bf(v.w);
        }
    } else {
        const unsigned short* Ws = (const unsigned short*)Wraw;
        for (int i = tid; i < TOT4; i += 256) {
            int idx = i * 4;
            int k = idx / FOUT;
            int n = idx & (FOUT - 1);
            short4v v = *(const short4v*)(const void*)(Ws + idx);
#pragma unroll
            for (int j = 0; j < 4; j++) bt[(n + j) * LDB + k] = ((const unsigned short*)&v)[j];
        }
    }

    const int wave = tid >> 6;
    const int lane = tid & 63;
    const int quad = lane >> 4;
    const int r16 = lane & 15;

    // A is internal bf16 [N][128]
    short8 afrag[2][4];
#pragma unroll
    for (int t = 0; t < 2; t++) {
        int arow = blockIdx.x * 128 + t * 64 + wave * 16 + r16;
        if (arow > Nrows - 1) arow = Nrows - 1;
        const unsigned short* Ap = (const unsigned short*)Araw + (size_t)arow * K + quad * 8;
#pragma unroll
        for (int kk = 0; kk < 4; kk++) afrag[t][kk] = *(const short8*)(const void*)(Ap + kk * 32);
    }

    __syncthreads();

    f32x4 acc[2][NT];
#pragma unroll
    for (int t = 0; t < 2; t++)
#pragma unroll
        for (int nt = 0; nt < NT; nt++) acc[t][nt] = (f32x4){0.f, 0.f, 0.f, 0.f};

#pragma unroll
    for (int kk = 0; kk < 4; kk++) {
#pragma unroll
        for (int nt = 0; nt < NT; nt++) {
            short8 b = *(const short8*)(const void*)(&bt[(nt * 16 + r16) * LDB + kk * 32 + quad * 8]);
#pragma unroll
            for (int t = 0; t < 2; t++)
                acc[t][nt] = __builtin_amdgcn_mfma_f32_16x16x32_bf16(afrag[t][kk], b, acc[t][nt], 0, 0, 0);
        }
    }

#pragma unroll
    for (int t = 0; t < 2; t++) {
#pragma unroll
        for (int nt = 0; nt < NT; nt++) {
#pragma unroll
            for (int r = 0; r < 4; r++) {
                float v = acc[t][nt][r];
                float o = __shfl_xor(v, 1, 64);
                int row = blockIdx.x * 128 + t * 64 + wave * 16 + quad * 4 + r;
                if (((lane & 1) == 0) && row < Nrows) {
                    __hip_bfloat162 pk;
                    pk.x = __float2bfloat16(v);
                    pk.y = __float2bfloat16(o);
                    *(__hip_bfloat162*)(out + (size_t)row * FOUT + nt * 16 + r16) = pk;
                }
            }
        }
    }
}

// ---------------- SpMM: wave per node, 4 edges in flight (16-lane groups, 16B row slices) ----------------

__global__ __launch_bounds__(256) void spmm128_kernel(const int2* __restrict__ edgedat,
                                                      const int* __restrict__ rowptr,
                                                      const int* __restrict__ counts,
                                                      const unsigned short* __restrict__ Hin,
                                                      unsigned short* __restrict__ Hout, int N) {
    int wid = (blockIdx.x * 256 + threadIdx.x) >> 6;
    if (wid >= N) return;
    int lane = threadIdx.x & 63;
    int grp = lane >> 4;
    int gl = lane & 15;
    int n = __builtin_amdgcn_readfirstlane(wid);
    int start = __builtin_amdgcn_readfirstlane(rowptr[n]);
    int len = __builtin_amdgcn_readfirstlane(counts[n]);
    const int2* ep = edgedat + start;

    float acc[8];
#pragma unroll
    for (int u = 0; u < 8; u++) acc[u] = 0.f;

    int j = 0;
    for (; j + 8 <= len; j += 8) {
        int2 e0 = ep[j + grp];
        int2 e1 = ep[j + 4 + grp];
        short8 h0 = *(const short8*)(const void*)(Hin + (size_t)e0.x * 128 + gl * 8);
        short8 h1 = *(const short8*)(const void*)(Hin + (size_t)e1.x * 128 + gl * 8);
        float w0 = __int_as_float(e0.y);
        float w1 = __int_as_float(e1.y);
#pragma unroll
        for (int u = 0; u < 8; u++) acc[u] += w0 * bf2f((unsigned short)h0[u]);
#pragma unroll
        for (int u = 0; u < 8; u++) acc[u] += w1 * bf2f((unsigned short)h1[u]);
    }
    for (; j + 4 <= len; j += 4) {
        int2 e = ep[j + grp];
        short8 h = *(const short8*)(const void*)(Hin + (size_t)e.x * 128 + gl * 8);
        float w = __int_as_float(e.y);
#pragma unroll
        for (int u = 0; u < 8; u++) acc[u] += w * bf2f((unsigned short)h[u]);
    }
    int rem = len - j;
    if (grp < rem) {
        int2 e = ep[j + grp];
        short8 h = *(const short8*)(const void*)(Hin + (size_t)e.x * 128 + gl * 8);
        float w = __int_as_float(e.y);
#pragma unroll
        for (int u = 0; u < 8; u++) acc[u] += w * bf2f((unsigned short)h[u]);
    }

#pragma unroll
    for (int u = 0; u < 8; u++) {
        acc[u] += __shfl_xor(acc[u], 16, 64);
        acc[u] += __shfl_xor(acc[u], 32, 64);
    }

    if (grp == 0) {
        short8 o;
#pragma unroll
        for (int u = 0; u < 8; u++) o[u] = (short)f2bf(fmaxf(acc[u], 0.f));
        *(short8*)(void*)(Hout + (size_t)n * 128 + gl * 8) = o;
    }
}

// ---------------- SpMM F=64 + relu + softmax: 8 edges in flight (8-lane groups) ----------------

__global__ __launch_bounds__(256) void spmm64_softmax_kernel(const int2* __restrict__ edgedat,
                                                             const int* __restrict__ rowptr,
                                                             const int* __restrict__ counts,
                                                             const unsigned short* __restrict__ Hin,
                                                             const int* __restrict__ flags,
                                                             void* __restrict__ Out, int N) {
    int wid = (blockIdx.x * 256 + threadIdx.x) >> 6;
    if (wid >= N) return;
    int lane = threadIdx.x & 63;
    int grp = lane >> 3;
    int gl = lane & 7;
    int n = __builtin_amdgcn_readfirstlane(wid);
    int start = __builtin_amdgcn_readfirstlane(rowptr[n]);
    int len = __builtin_amdgcn_readfirstlane(counts[n]);
    const int2* ep = edgedat + start;

    float acc[8];
#pragma unroll
    for (int u = 0; u < 8; u++) acc[u] = 0.f;

    int j = 0;
    for (; j + 16 <= len; j += 16) {
        int2 e0 = ep[j + grp];
        int2 e1 = ep[j + 8 + grp];
        short8 h0 = *(const short8*)(const void*)(Hin + (size_t)e0.x * 64 + gl * 8);
        short8 h1 = *(const short8*)(const void*)(Hin + (size_t)e1.x * 64 + gl * 8);
        float w0 = __int_as_float(e0.y);
        float w1 = __int_as_float(e1.y);
#pragma unroll
        for (int u = 0; u < 8; u++) acc[u] += w0 * bf2f((unsigned short)h0[u]);
#pragma unroll
        for (int u = 0; u < 8; u++) acc[u] += w1 * bf2f((unsigned short)h1[u]);
    }
    for (; j + 8 <= len; j += 8) {
        int2 e = ep[j + grp];
        short8 h = *(const short8*)(const void*)(Hin + (size_t)e.x * 64 + gl * 8);
        float w = __int_as_float(e.y);
#pragma unroll
        for (int u = 0; u < 8; u++) acc[u] += w * bf2f((unsigned short)h[u]);
    }
    int rem = len - j;
    if (grp < rem) {
        int2 e = ep[j + grp];
        short8 h = *(const short8*)(const void*)(Hin + (size_t)e.x * 64 + gl * 8);
        float w = __int_as_float(e.y);
#pragma unroll
        for (int u = 0; u < 8; u++) acc[u] += w * bf2f((unsigned short)h[u]);
    }

#pragma unroll
    for (int u = 0; u < 8; u++) {
        acc[u] += __shfl_xor(acc[u], 8, 64);
        acc[u] += __shfl_xor(acc[u], 16, 64);
        acc[u] += __shfl_xor(acc[u], 32, 64);
    }

#pragma unroll
    for (int u = 0; u < 8; u++) acc[u] = fmaxf(acc[u], 0.f);

    float m = acc[0];
#pragma unroll
    for (int u = 1; u < 8; u++) m = fmaxf(m, acc[u]);
#pragma unroll
    for (int off = 1; off < 8; off <<= 1) m = fmaxf(m, __shfl_xor(m, off, 64));

    float ex[8];
    float s = 0.f;
#pragma unroll
    for (int u = 0; u < 8; u++) {
        ex[u] = __expf(acc[u] - m);
        s += ex[u];
    }
#pragma unroll
    for (int off = 1; off < 8; off <<= 1) s += __shfl_xor(s, off, 64);
    float inv = 1.0f / s;

    if (grp == 0) {
        if (flags[0]) {
            float* op = (float*)Out + (size_t)n * 64 + gl * 8;
            float4 v0, v1;
            v0.x = ex[0] * inv; v0.y = ex[1] * inv; v0.z = ex[2] * inv; v0.w = ex[3] * inv;
            v1.x = ex[4] * inv; v1.y = ex[5] * inv; v1.z = ex[6] * inv; v1.w = ex[7] * inv;
            *(float4*)(void*)op = v0;
            *(float4*)(void*)(op + 4) = v1;
        } else {
            short8 o;
#pragma unroll
            for (int u = 0; u < 8; u++) o[u] = (short)f2bf(ex[u] * inv);
            *(short8*)(void*)((unsigned short*)Out + (size_t)n * 64 + gl * 8) = o;
        }
    }
}

// ---------------- launch ----------------

extern "C" void kernel_launch(void* const* d_in, const int* in_sizes, int n_in,
                              void* d_out, int out_size, void* d_ws, size_t ws_size,
                              hipStream_t stream) {
    const void* X  = d_in[0];                       // [N,128] bf16 or fp32
    const int*  ei = (const int*)d_in[1];           // [2,E] int32 or int64
    const void* W1 = d_in[2];                       // [128,128]
    const void* W2 = d_in[3];                       // [128,128]
    const void* W3 = d_in[4];                       // [128,64]

    const int N = in_sizes[0] / 128;   // 50000
    const int E = in_sizes[1] / 2;     // 800000

    char* ws = (char*)d_ws;
    size_t off = 0;
    int* counts = (int*)(ws + off);   off += ws_align((size_t)N * 4);
    int* total  = (int*)(ws + off);   off += ws_align(64);
    const size_t zero_bytes = off;    // counts + total need zeroing
    int* flags    = (int*)(ws + off);   off += ws_align(64);
    int* rowptr   = (int*)(ws + off);   off += ws_align((size_t)N * 4);
    float* dinv   = (float*)(ws + off); off += ws_align((size_t)N * 4);
    int* loff     = (int*)(ws + off);   off += ws_align((size_t)E * 4);
    int2* edgedat = (int2*)(ws + off);  off += ws_align((size_t)E * 8);
    unsigned short* HA = (unsigned short*)(ws + off); off += ws_align((size_t)N * 128 * 2);
    unsigned short* HB = (unsigned short*)(ws + off); off += ws_align((size_t)N * 128 * 2);

    hipMemsetAsync(d_ws, 0, zero_bytes, stream);

    const int gblocks = (N + 127) / 128;       // 391
    const int hblocks = (E + 255) / 256;       // 3125
    const int sblocks = (N * 64 + 255) / 256;

    // K1: gemm1 (X @ W1 -> HA) in parallel with hist (counts/loff) + flag write
    gemm1_hist_kernel<<<gblocks + hblocks, 256, 0, stream>>>(
        X, (const unsigned short*)W1, ei, counts, loff, flags, HA, N, E, gblocks);
    alloc_kernel<<<(N + 255) / 256, 256, 0, stream>>>(counts, dinv, rowptr, total, N);
    fill_kernel<<<hblocks, 256, 0, stream>>>(ei, flags, dinv, rowptr, loff, edgedat, E);

    // layer 1 aggregate: HB = relu(A_norm HA)
    spmm128_kernel<<<sblocks, 256, 0, stream>>>(edgedat, rowptr, counts, HA, HB, N);
    // layer 2
    gemm_kernel<128><<<gblocks, 256, 0, stream>>>(HB, W2, flags, HA, N);
    spmm128_kernel<<<sblocks, 256, 0, stream>>>(edgedat, rowptr, counts, HA, HB, N);
    // layer 3 (F_out = 64) + relu + softmax
    gemm_kernel<64><<<gblocks, 256, 0, stream>>>(HB, W3, flags, HA, N);
    spmm64_softmax_kernel<<<sblocks, 256, 0, stream>>>(edgedat, rowptr, counts, HA, flags, d_out, N);
}